// Round 1
// baseline (653.842 us; speedup 1.0000x reference)
//
#include <hip/hip_runtime.h>

#define S_LEN 2048
#define DMODEL 1024
#define H_CNT 16
#define DK 64
#define BATCH 4

typedef __attribute__((ext_vector_type(8))) short short8;
typedef __attribute__((ext_vector_type(4))) float f32x4;

static __device__ __forceinline__ short f2bf(float f) {
  union { float f; unsigned u; } x; x.f = f;
  unsigned r = x.u + 0x7fffu + ((x.u >> 16) & 1u);
  return (short)(r >> 16);
}

// ---------------- cast fp32 -> bf16, 8 elems/thread ----------------
__global__ __launch_bounds__(256) void cast_kernel(const float* __restrict__ src,
                                                   short* __restrict__ dst, int n8) {
  int i = blockIdx.x * 256 + threadIdx.x;
  if (i >= n8) return;
  const float4* s4 = (const float4*)src;
  float4 a = s4[2 * i], b = s4[2 * i + 1];
  short8 o;
  o[0] = f2bf(a.x); o[1] = f2bf(a.y); o[2] = f2bf(a.z); o[3] = f2bf(a.w);
  o[4] = f2bf(b.x); o[5] = f2bf(b.y); o[6] = f2bf(b.z); o[7] = f2bf(b.w);
  ((short8*)dst)[i] = o;
}

// ---------------- GEMM: C[M,N] = A[M,K] * B[N,K]^T + bias ----------------
// MODE 0: out bf16 scattered to (B,H,S,dk)      (for Q, K)
// MODE 1: out bf16 scattered to (B,H,dk,S)      (for V transposed)
// MODE 2: out fp32 row-major [M,N]              (final projection)
template <int MODE>
__global__ __launch_bounds__(256) void gemm_bt(const short* __restrict__ A,
                                               const short* __restrict__ B,
                                               const float* __restrict__ bias,
                                               void* __restrict__ Cout,
                                               int M, int N, int K) {
  __shared__ short As[128][32];
  __shared__ short Bs[128][32];
  const int tid = threadIdx.x;
  const int lane = tid & 63, wid = tid >> 6;
  const int m0 = blockIdx.y * 128, n0 = blockIdx.x * 128;
  const int wr = (wid >> 1) * 64, wc = (wid & 1) * 64;
  const int lrow = lane & 15, lk8 = (lane >> 4) * 8;
  const int sr = tid >> 2, sk = (tid & 3) * 8;

  f32x4 acc[4][4] = {};

  for (int k0 = 0; k0 < K; k0 += 32) {
    *(short8*)(&As[sr][sk])      = *(const short8*)(&A[(size_t)(m0 + sr) * K + k0 + sk]);
    *(short8*)(&As[sr + 64][sk]) = *(const short8*)(&A[(size_t)(m0 + sr + 64) * K + k0 + sk]);
    *(short8*)(&Bs[sr][sk])      = *(const short8*)(&B[(size_t)(n0 + sr) * K + k0 + sk]);
    *(short8*)(&Bs[sr + 64][sk]) = *(const short8*)(&B[(size_t)(n0 + sr + 64) * K + k0 + sk]);
    __syncthreads();
    short8 af[4], bfr[4];
#pragma unroll
    for (int m = 0; m < 4; m++) af[m] = *(const short8*)(&As[wr + m * 16 + lrow][lk8]);
#pragma unroll
    for (int n = 0; n < 4; n++) bfr[n] = *(const short8*)(&Bs[wc + n * 16 + lrow][lk8]);
#pragma unroll
    for (int m = 0; m < 4; m++)
#pragma unroll
      for (int n = 0; n < 4; n++)
        acc[m][n] = __builtin_amdgcn_mfma_f32_16x16x32_bf16(af[m], bfr[n], acc[m][n], 0, 0, 0);
    __syncthreads();
  }

#pragma unroll
  for (int n = 0; n < 4; n++) {
    int col = n0 + wc + n * 16 + lrow;
    float bv = bias[col];
#pragma unroll
    for (int m = 0; m < 4; m++) {
      int rbase = m0 + wr + m * 16 + (lane >> 4) * 4;
#pragma unroll
      for (int i = 0; i < 4; i++) {
        int row = rbase + i;
        float val = acc[m][n][i] + bv;
        if (MODE == 2) {
          ((float*)Cout)[(size_t)row * N + col] = val;
        } else {
          int b = row >> 11, s2 = row & 2047, h = col >> 6, d = col & 63;
          short* o = (short*)Cout;
          if (MODE == 0)
            o[((size_t)(b * H_CNT + h) * S_LEN + s2) * DK + d] = f2bf(val);
          else
            o[((size_t)(b * H_CNT + h) * DK + d) * S_LEN + s2] = f2bf(val);
        }
      }
    }
  }
}

// ---------------- causal flash attention ----------------
// grid: (S/64, B*H), block 256 (4 waves x 16 q-rows). KV tile = 32.
// Q,K: (B,H,S,dk) bf16.  Vt: (B,H,dk,S) bf16.  Out: (B,S,D) bf16.
__global__ __launch_bounds__(256) void attn_kernel(const short* __restrict__ Q,
                                                   const short* __restrict__ Kc,
                                                   const short* __restrict__ Vt,
                                                   short* __restrict__ Oout) {
  const int bh = blockIdx.y;
  const int wid = threadIdx.x >> 6, lane = threadIdx.x & 63;
  const int q0 = blockIdx.x * 64 + wid * 16;
  const int lrow = lane & 15, g = lane >> 4, lk8 = g * 8;

  const short* Qb = Q + (size_t)bh * S_LEN * DK;
  const short* Kb = Kc + (size_t)bh * S_LEN * DK;
  const short* Vb = Vt + (size_t)bh * DK * S_LEN;

  __shared__ short Pbuf[4][16][32];
  short(*sp)[32] = Pbuf[wid];

  short8 aq[2];
  aq[0] = *(const short8*)(&Qb[(q0 + lrow) * DK + lk8]);
  aq[1] = *(const short8*)(&Qb[(q0 + lrow) * DK + 32 + lk8]);

  f32x4 o[4] = {};
  float mrun[4], lrun[4];
#pragma unroll
  for (int i = 0; i < 4; i++) { mrun[i] = -INFINITY; lrun[i] = 0.f; }

  const float scale = 0.125f;  // 1/sqrt(64)
  const int ntiles = (q0 + 15) / 32 + 1;

  for (int t = 0; t < ntiles; t++) {
    const int kv0 = t * 32;
    f32x4 s[2] = {};
#pragma unroll
    for (int c = 0; c < 2; c++) {
      short8 bk0 = *(const short8*)(&Kb[(kv0 + c * 16 + lrow) * DK + lk8]);
      short8 bk1 = *(const short8*)(&Kb[(kv0 + c * 16 + lrow) * DK + 32 + lk8]);
      s[c] = __builtin_amdgcn_mfma_f32_16x16x32_bf16(aq[0], bk0, s[c], 0, 0, 0);
      s[c] = __builtin_amdgcn_mfma_f32_16x16x32_bf16(aq[1], bk1, s[c], 0, 0, 0);
    }
    // scale + causal mask
#pragma unroll
    for (int i = 0; i < 4; i++) {
      int row = q0 + 4 * g + i;
#pragma unroll
      for (int c = 0; c < 2; c++) {
        int colg = kv0 + c * 16 + lrow;
        float v = s[c][i] * scale;
        if (colg > row) v = -INFINITY;
        s[c][i] = v;
      }
    }
    // online softmax (per-row over 16 lanes of the group)
    float alpha[4];
#pragma unroll
    for (int i = 0; i < 4; i++) {
      float rm = fmaxf(s[0][i], s[1][i]);
#pragma unroll
      for (int off = 1; off < 16; off <<= 1) rm = fmaxf(rm, __shfl_xor(rm, off, 64));
      float mnew = fmaxf(mrun[i], rm);
      alpha[i] = __expf(mrun[i] - mnew);
      mrun[i] = mnew;
      float p0 = __expf(s[0][i] - mnew);
      float p1 = __expf(s[1][i] - mnew);
      s[0][i] = p0; s[1][i] = p1;
      float r = p0 + p1;
#pragma unroll
      for (int off = 1; off < 16; off <<= 1) r += __shfl_xor(r, off, 64);
      lrun[i] = lrun[i] * alpha[i] + r;
    }
#pragma unroll
    for (int co = 0; co < 4; co++)
#pragma unroll
      for (int i = 0; i < 4; i++) o[co][i] *= alpha[i];

    // P -> LDS (transpose to A-fragment layout), per-wave buffer, no block barrier
#pragma unroll
    for (int c = 0; c < 2; c++)
#pragma unroll
      for (int i = 0; i < 4; i++)
        sp[4 * g + i][c * 16 + lrow] = f2bf(s[c][i]);
    asm volatile("s_waitcnt lgkmcnt(0)" ::: "memory");
    short8 pf = *(const short8*)(&sp[lrow][lk8]);

    // PV: O[16 x 64] += P[16 x 32] * V[32 x 64]  (V supplied transposed)
#pragma unroll
    for (int co = 0; co < 4; co++) {
      short8 vf = *(const short8*)(&Vb[(size_t)(co * 16 + lrow) * S_LEN + kv0 + lk8]);
      o[co] = __builtin_amdgcn_mfma_f32_16x16x32_bf16(pf, vf, o[co], 0, 0, 0);
    }
  }

  // epilogue: normalize, write (B,S,D) bf16
  const int b = bh >> 4, h = bh & 15;
#pragma unroll
  for (int co = 0; co < 4; co++) {
#pragma unroll
    for (int i = 0; i < 4; i++) {
      int row = q0 + 4 * g + i;
      int d = co * 16 + lrow;
      float val = o[co][i] / lrun[i];
      Oout[((size_t)b * S_LEN + row) * DMODEL + h * DK + d] = f2bf(val);
    }
  }
}

// ---------------- launcher ----------------
extern "C" void kernel_launch(void* const* d_in, const int* in_sizes, int n_in,
                              void* d_out, int out_size, void* d_ws, size_t ws_size,
                              hipStream_t stream) {
  (void)in_sizes; (void)n_in; (void)out_size; (void)ws_size;
  const float* query = (const float*)d_in[0];
  const float* key_i = (const float*)d_in[1];
  const float* value = (const float*)d_in[2];
  const float* w_q = (const float*)d_in[4];
  const float* b_q = (const float*)d_in[5];
  const float* w_k = (const float*)d_in[6];
  const float* b_k = (const float*)d_in[7];
  const float* w_v = (const float*)d_in[8];
  const float* b_v = (const float*)d_in[9];
  const float* w_o = (const float*)d_in[10];
  const float* b_o = (const float*)d_in[11];

  const size_t XE = (size_t)BATCH * S_LEN * DMODEL;  // 8388608
  const size_t WE = (size_t)DMODEL * DMODEL;         // 1048576

  short* xq = (short*)d_ws;
  short* xk = xq + XE;
  short* xv = xk + XE;
  short* wq = xv + XE;
  short* wk = wq + WE;
  short* wv = wk + WE;
  short* wo = wv + WE;
  short* qb = wo + WE;
  short* kb = qb + XE;
  short* vtb = kb + XE;
  short* attnb = xq;  // reuse: xq dead after Q projection

  const int M = BATCH * S_LEN;  // 8192

  int n8x = (int)(XE / 8), n8w = (int)(WE / 8);
  cast_kernel<<<dim3((n8x + 255) / 256), 256, 0, stream>>>(query, xq, n8x);
  cast_kernel<<<dim3((n8x + 255) / 256), 256, 0, stream>>>(key_i, xk, n8x);
  cast_kernel<<<dim3((n8x + 255) / 256), 256, 0, stream>>>(value, xv, n8x);
  cast_kernel<<<dim3((n8w + 255) / 256), 256, 0, stream>>>(w_q, wq, n8w);
  cast_kernel<<<dim3((n8w + 255) / 256), 256, 0, stream>>>(w_k, wk, n8w);
  cast_kernel<<<dim3((n8w + 255) / 256), 256, 0, stream>>>(w_v, wv, n8w);
  cast_kernel<<<dim3((n8w + 255) / 256), 256, 0, stream>>>(w_o, wo, n8w);

  dim3 gg(DMODEL / 128, M / 128);
  gemm_bt<0><<<gg, 256, 0, stream>>>(xq, wq, b_q, qb, M, DMODEL, DMODEL);
  gemm_bt<0><<<gg, 256, 0, stream>>>(xk, wk, b_k, kb, M, DMODEL, DMODEL);
  gemm_bt<1><<<gg, 256, 0, stream>>>(xv, wv, b_v, vtb, M, DMODEL, DMODEL);

  attn_kernel<<<dim3(S_LEN / 64, BATCH * H_CNT), 256, 0, stream>>>(qb, kb, vtb, attnb);

  gemm_bt<2><<<gg, 256, 0, stream>>>(attnb, wo, b_o, d_out, M, DMODEL, DMODEL);
}

// Round 2
// 302.020 us; speedup vs baseline: 2.1649x; 2.1649x over previous
//
#include <hip/hip_runtime.h>

#define S_LEN 2048
#define DMODEL 1024
#define H_CNT 16
#define DK 64
#define BATCH 4

typedef __attribute__((ext_vector_type(8))) short short8;
typedef __attribute__((ext_vector_type(4))) float f32x4;
typedef __attribute__((ext_vector_type(16))) float f32x16;

static __device__ __forceinline__ short f2bf(float f) {
  union { float f; unsigned u; } x; x.f = f;
  unsigned r = x.u + 0x7fffu + ((x.u >> 16) & 1u);
  return (short)(r >> 16);
}

static __device__ __forceinline__ unsigned cvt_pk_bf16(float lo, float hi) {
  unsigned r;
  asm("v_cvt_pk_bf16_f32 %0, %1, %2" : "=v"(r) : "v"(lo), "v"(hi));
  return r;
}

// ---------------- cast fp32 -> bf16, 8 elems/thread ----------------
__global__ __launch_bounds__(256) void cast_kernel(const float* __restrict__ src,
                                                   short* __restrict__ dst, int n8) {
  int i = blockIdx.x * 256 + threadIdx.x;
  if (i >= n8) return;
  const float4* s4 = (const float4*)src;
  float4 a = s4[2 * i], b = s4[2 * i + 1];
  short8 o;
  o[0] = f2bf(a.x); o[1] = f2bf(a.y); o[2] = f2bf(a.z); o[3] = f2bf(a.w);
  o[4] = f2bf(b.x); o[5] = f2bf(b.y); o[6] = f2bf(b.z); o[7] = f2bf(b.w);
  ((short8*)dst)[i] = o;
}

// ---------------- GEMM: C[M,N] = (A[M,K] * B[N,K]^T + bias) * scl ----------------
// MODE 0: out bf16 scattered to (B,H,S,dk)      (for Q, K)
// MODE 1: out bf16 scattered to (B,H,dk,S)      (for V transposed)
// MODE 2: out fp32 row-major [M,N]              (final projection)
template <int MODE>
__global__ __launch_bounds__(256) void gemm_bt(const short* __restrict__ A,
                                               const short* __restrict__ B,
                                               const float* __restrict__ bias,
                                               void* __restrict__ Cout,
                                               int M, int N, int K, float scl) {
  __shared__ short As[128][32];
  __shared__ short Bs[128][32];
  const int tid = threadIdx.x;
  const int lane = tid & 63, wid = tid >> 6;
  const int m0 = blockIdx.y * 128, n0 = blockIdx.x * 128;
  const int wr = (wid >> 1) * 64, wc = (wid & 1) * 64;
  const int lrow = lane & 15, lk8 = (lane >> 4) * 8;
  const int sr = tid >> 2, sk = (tid & 3) * 8;

  f32x4 acc[4][4] = {};

  for (int k0 = 0; k0 < K; k0 += 32) {
    *(short8*)(&As[sr][sk])      = *(const short8*)(&A[(size_t)(m0 + sr) * K + k0 + sk]);
    *(short8*)(&As[sr + 64][sk]) = *(const short8*)(&A[(size_t)(m0 + sr + 64) * K + k0 + sk]);
    *(short8*)(&Bs[sr][sk])      = *(const short8*)(&B[(size_t)(n0 + sr) * K + k0 + sk]);
    *(short8*)(&Bs[sr + 64][sk]) = *(const short8*)(&B[(size_t)(n0 + sr + 64) * K + k0 + sk]);
    __syncthreads();
    short8 af[4], bfr[4];
#pragma unroll
    for (int m = 0; m < 4; m++) af[m] = *(const short8*)(&As[wr + m * 16 + lrow][lk8]);
#pragma unroll
    for (int n = 0; n < 4; n++) bfr[n] = *(const short8*)(&Bs[wc + n * 16 + lrow][lk8]);
#pragma unroll
    for (int m = 0; m < 4; m++)
#pragma unroll
      for (int n = 0; n < 4; n++)
        acc[m][n] = __builtin_amdgcn_mfma_f32_16x16x32_bf16(af[m], bfr[n], acc[m][n], 0, 0, 0);
    __syncthreads();
  }

#pragma unroll
  for (int n = 0; n < 4; n++) {
    int col = n0 + wc + n * 16 + lrow;
    float bv = bias[col];
#pragma unroll
    for (int m = 0; m < 4; m++) {
      int rbase = m0 + wr + m * 16 + (lane >> 4) * 4;
#pragma unroll
      for (int i = 0; i < 4; i++) {
        int row = rbase + i;
        float val = (acc[m][n][i] + bv) * scl;
        if (MODE == 2) {
          ((float*)Cout)[(size_t)row * N + col] = val;
        } else {
          int b = row >> 11, s2 = row & 2047, h = col >> 6, d = col & 63;
          short* o = (short*)Cout;
          if (MODE == 0)
            o[((size_t)(b * H_CNT + h) * S_LEN + s2) * DK + d] = f2bf(val);
          else
            o[((size_t)(b * H_CNT + h) * DK + d) * S_LEN + s2] = f2bf(val);
        }
      }
    }
  }
}

// ---------------- causal flash attention v2 ----------------
// Swapped QK^T (32x32x16 MFMA), in-register softmax, no LDS, no barriers.
// grid: (16, B*H), block 256 = 4 waves. Wave w handles q-tile {j,31-j,32+j,63-j}[w]
// (perfect causal work balance: 130 kv-tiles per block).
// Q is pre-scaled by 0.125*log2(e) in its projection; softmax in exp2 domain.
// Q,K: (B,H,S,64) bf16.  Vt: (B,H,64,S) bf16.  Out: (B,S,1024) bf16.
__global__ __launch_bounds__(256, 4) void attn2_kernel(const short* __restrict__ Q,
                                                       const short* __restrict__ Kc,
                                                       const short* __restrict__ Vt,
                                                       short* __restrict__ Oout) {
  const int bh = blockIdx.y;
  const int j = blockIdx.x;
  const int wid = threadIdx.x >> 6, lane = threadIdx.x & 63;
  const int qt = (wid == 0) ? j : (wid == 1) ? (31 - j) : (wid == 2) ? (32 + j) : (63 - j);
  const int q0 = qt * 32;
  const int ql = lane & 31, hl = lane >> 5;

  const short* Qb = Q + (size_t)bh * S_LEN * DK;
  const short* Kb = Kc + (size_t)bh * S_LEN * DK;
  const short* Vb = Vt + (size_t)bh * DK * S_LEN;

  // Q B-fragments: lane = column q0+ql, k elems = kk*16 + hl*8 + (0..7)
  short8 qf[4];
#pragma unroll
  for (int kk = 0; kk < 4; kk++)
    qf[kk] = *(const short8*)(&Qb[(q0 + ql) * DK + kk * 16 + hl * 8]);

  f32x16 oacc[2] = {};  // O^T tiles: td*32 + row(reg), col = q
  float mr = -1e30f, lr = 0.f;

  const int ntiles = qt + 1;
  for (int t = 0; t < ntiles; t++) {
    const int kv0 = t * 32;
    // S^T[kv, q] = sum_k K[kv,k] * Q[q,k]
    f32x16 st = {};
#pragma unroll
    for (int kk = 0; kk < 4; kk++) {
      short8 kf = *(const short8*)(&Kb[(kv0 + ql) * DK + kk * 16 + hl * 8]);
      st = __builtin_amdgcn_mfma_f32_32x32x16_bf16(kf, qf[kk], st, 0, 0, 0);
    }
    // hoist V loads to hide latency under softmax VALU work
    short8 vf[2][2];
#pragma unroll
    for (int td = 0; td < 2; td++)
#pragma unroll
      for (int kk = 0; kk < 2; kk++)
        vf[td][kk] = *(const short8*)(&Vb[(size_t)(td * 32 + ql) * S_LEN + kv0 + kk * 16 + hl * 8]);

    float p[16];
#pragma unroll
    for (int r = 0; r < 16; r++) p[r] = st[r];
    if (t == ntiles - 1) {  // only the diagonal tile needs masking
#pragma unroll
      for (int r = 0; r < 16; r++) {
        int kvr = (r & 3) + 8 * (r >> 2) + 4 * hl;
        if (kvr > ql) p[r] = -1e30f;
      }
    }
    // row max over this lane's 16 kv values + cross-half combine
    float pm = p[0];
#pragma unroll
    for (int r = 1; r < 16; r++) pm = fmaxf(pm, p[r]);
    pm = fmaxf(pm, __shfl_xor(pm, 32, 64));
    // defer-max: only rescale when max grew by > 8 (values bounded by 2^8)
    if (!__all(pm <= mr + 8.f)) {
      float mnew = fmaxf(mr, pm);
      float al = __builtin_amdgcn_exp2f(mr - mnew);
      lr *= al;
#pragma unroll
      for (int td = 0; td < 2; td++)
#pragma unroll
        for (int r = 0; r < 16; r++) oacc[td][r] *= al;
      mr = mnew;
    }
    float rs = 0.f;
#pragma unroll
    for (int r = 0; r < 16; r++) {
      p[r] = __builtin_amdgcn_exp2f(p[r] - mr);
      rs += p[r];
    }
    rs += __shfl_xor(rs, 32, 64);
    lr += rs;

    // pack P to bf16 pairs: w[tt] = rows {(2tt&3)+8*(tt>>1), +1} + 4*hl
    unsigned w[8];
#pragma unroll
    for (int tt = 0; tt < 8; tt++) w[tt] = cvt_pk_bf16(p[2 * tt], p[2 * tt + 1]);
    // redistribute halves into PV B-fragments (rows kk*16 + 8*hl + j)
    union { short8 s; unsigned u[4]; } bf0, bf1;
    {
      unsigned xa = __shfl_xor((int)w[2], 32, 64), xb = __shfl_xor((int)w[0], 32, 64);
      bf0.u[0] = hl ? xa : w[0];
      bf0.u[2] = hl ? w[2] : xb;
    }
    {
      unsigned xa = __shfl_xor((int)w[3], 32, 64), xb = __shfl_xor((int)w[1], 32, 64);
      bf0.u[1] = hl ? xa : w[1];
      bf0.u[3] = hl ? w[3] : xb;
    }
    {
      unsigned xa = __shfl_xor((int)w[6], 32, 64), xb = __shfl_xor((int)w[4], 32, 64);
      bf1.u[0] = hl ? xa : w[4];
      bf1.u[2] = hl ? w[6] : xb;
    }
    {
      unsigned xa = __shfl_xor((int)w[7], 32, 64), xb = __shfl_xor((int)w[5], 32, 64);
      bf1.u[1] = hl ? xa : w[5];
      bf1.u[3] = hl ? w[7] : xb;
    }

    // O^T[d, q] += V^T[d, kv] * P^T[kv, q]   (Vt is (dk, S) row-major = V^T)
#pragma unroll
    for (int td = 0; td < 2; td++) {
      oacc[td] = __builtin_amdgcn_mfma_f32_32x32x16_bf16(vf[td][0], bf0.s, oacc[td], 0, 0, 0);
      oacc[td] = __builtin_amdgcn_mfma_f32_32x32x16_bf16(vf[td][1], bf1.s, oacc[td], 0, 0, 0);
    }
  }

  // epilogue: normalize and write (B,S,DMODEL) bf16 as packed u32 pairs
  const float inv = __builtin_amdgcn_rcpf(lr);
  const int b = bh >> 4, h = bh & 15;
  unsigned* ob = (unsigned*)Oout + ((size_t)b * S_LEN + q0 + ql) * (DMODEL / 2) + h * (DK / 2);
#pragma unroll
  for (int td = 0; td < 2; td++)
#pragma unroll
    for (int tt = 0; tt < 8; tt++) {
      unsigned pkv = cvt_pk_bf16(oacc[td][2 * tt] * inv, oacc[td][2 * tt + 1] * inv);
      ob[td * 16 + (tt & 1) + 4 * (tt >> 1) + 2 * hl] = pkv;
    }
}

// ---------------- launcher ----------------
extern "C" void kernel_launch(void* const* d_in, const int* in_sizes, int n_in,
                              void* d_out, int out_size, void* d_ws, size_t ws_size,
                              hipStream_t stream) {
  (void)in_sizes; (void)n_in; (void)out_size; (void)ws_size;
  const float* query = (const float*)d_in[0];
  const float* key_i = (const float*)d_in[1];
  const float* value = (const float*)d_in[2];
  const float* w_q = (const float*)d_in[4];
  const float* b_q = (const float*)d_in[5];
  const float* w_k = (const float*)d_in[6];
  const float* b_k = (const float*)d_in[7];
  const float* w_v = (const float*)d_in[8];
  const float* b_v = (const float*)d_in[9];
  const float* w_o = (const float*)d_in[10];
  const float* b_o = (const float*)d_in[11];

  const size_t XE = (size_t)BATCH * S_LEN * DMODEL;  // 8388608
  const size_t WE = (size_t)DMODEL * DMODEL;         // 1048576

  short* xq = (short*)d_ws;
  short* xk = xq + XE;
  short* xv = xk + XE;
  short* wq = xv + XE;
  short* wk = wq + WE;
  short* wv = wk + WE;
  short* wo = wv + WE;
  short* qb = wo + WE;
  short* kb = qb + XE;
  short* vtb = kb + XE;
  short* attnb = xq;  // reuse: xq dead after Q projection

  const int M = BATCH * S_LEN;  // 8192

  int n8x = (int)(XE / 8), n8w = (int)(WE / 8);
  cast_kernel<<<dim3((n8x + 255) / 256), 256, 0, stream>>>(query, xq, n8x);
  cast_kernel<<<dim3((n8x + 255) / 256), 256, 0, stream>>>(key_i, xk, n8x);
  cast_kernel<<<dim3((n8x + 255) / 256), 256, 0, stream>>>(value, xv, n8x);
  cast_kernel<<<dim3((n8w + 255) / 256), 256, 0, stream>>>(w_q, wq, n8w);
  cast_kernel<<<dim3((n8w + 255) / 256), 256, 0, stream>>>(w_k, wk, n8w);
  cast_kernel<<<dim3((n8w + 255) / 256), 256, 0, stream>>>(w_v, wv, n8w);
  cast_kernel<<<dim3((n8w + 255) / 256), 256, 0, stream>>>(w_o, wo, n8w);

  // Q pre-scaled by 1/sqrt(dk) * log2(e) so attention works in exp2 domain
  const float qscale = 0.125f * 1.44269504088896f;

  dim3 gg(DMODEL / 128, M / 128);
  gemm_bt<0><<<gg, 256, 0, stream>>>(xq, wq, b_q, qb, M, DMODEL, DMODEL, qscale);
  gemm_bt<0><<<gg, 256, 0, stream>>>(xk, wk, b_k, kb, M, DMODEL, DMODEL, 1.f);
  gemm_bt<1><<<gg, 256, 0, stream>>>(xv, wv, b_v, vtb, M, DMODEL, DMODEL, 1.f);

  attn2_kernel<<<dim3(16, BATCH * H_CNT), 256, 0, stream>>>(qb, kb, vtb, attnb);

  gemm_bt<2><<<gg, 256, 0, stream>>>(attnb, wo, b_o, d_out, M, DMODEL, DMODEL, 1.f);
}

// Round 6
// 277.995 us; speedup vs baseline: 2.3520x; 1.0864x over previous
//
#include <hip/hip_runtime.h>

#define S_LEN 2048
#define DMODEL 1024
#define H_CNT 16
#define DK 64
#define BATCH 4

typedef __attribute__((ext_vector_type(8))) short short8;
typedef __attribute__((ext_vector_type(4))) float f32x4;
typedef __attribute__((ext_vector_type(16))) float f32x16;

static __device__ __forceinline__ short f2bf(float f) {
  union { float f; unsigned u; } x; x.f = f;
  unsigned r = x.u + 0x7fffu + ((x.u >> 16) & 1u);
  return (short)(r >> 16);
}

static __device__ __forceinline__ unsigned cvt_pk_bf16(float lo, float hi) {
  unsigned r;
  asm("v_cvt_pk_bf16_f32 %0, %1, %2" : "=v"(r) : "v"(lo), "v"(hi));
  return r;
}

static __device__ __forceinline__ void gl_lds16(const short* g, short* l) {
  __builtin_amdgcn_global_load_lds((const __attribute__((address_space(1))) void*)g,
                                   (__attribute__((address_space(3))) void*)l, 16, 0, 0);
}

// ---------------- cast fp32 -> bf16, 8 elems/thread ----------------
__global__ __launch_bounds__(256) void cast_kernel(const float* __restrict__ src,
                                                   short* __restrict__ dst, int n8) {
  int i = blockIdx.x * 256 + threadIdx.x;
  if (i >= n8) return;
  const float4* s4 = (const float4*)src;
  float4 a = s4[2 * i], b = s4[2 * i + 1];
  short8 o;
  o[0] = f2bf(a.x); o[1] = f2bf(a.y); o[2] = f2bf(a.z); o[3] = f2bf(a.w);
  o[4] = f2bf(b.x); o[5] = f2bf(b.y); o[6] = f2bf(b.z); o[7] = f2bf(b.w);
  ((short8*)dst)[i] = o;
}

// ---------------- GEMM v2: C[M,N] = A[M,K] * B[N,K]^T (+bias)*scl ----------------
// (Proven output-identical to the round-2 GEMM by the r3==r4 absmax identity.)
// 128x64 tile, BK=32, 4 waves (each 32x64), global_load_lds 16B staging, XCD swizzle.
// MODE 0: A=x, B=w. out bf16 -> (B,H,S,dk). bias[col], then *scl.  (Q, K)
// MODE 1: A=w, B=x. out bf16 -> (B,H,dk,S) = V^T. bias[row].       (V)
// MODE 2: A=attn, B=w. out fp32 row-major [M,N]. bias[col].        (final)
// grid MUST be 1024 blocks; MODE1: M=1024,N=8192; else M=8192,N=1024.
template <int MODE>
__global__ __launch_bounds__(256) void gemm_bt(const short* __restrict__ A,
                                               const short* __restrict__ B,
                                               const float* __restrict__ bias,
                                               void* __restrict__ Cout,
                                               int M, int N, int K, float scl) {
  __shared__ short Sab[(128 + 64) * 32];  // As: rows 0..127, Bs: rows 128..191
  const int tid = threadIdx.x;
  const int lane = tid & 63, wid = tid >> 6;
  // bijective XCD swizzle: 1024 blocks -> 128 contiguous work items per XCD
  const int lin = blockIdx.x;
  const int w = (lin & 7) * 128 + (lin >> 3);
  int bx, by;
  if (MODE == 1) { bx = w >> 3; by = w & 7; }      // XCD owns 16-bx chunk, all by
  else           { bx = w & 15; by = w >> 4; }     // XCD owns 8-by chunk, all bx
  const int m0 = by * 128, n0 = bx * 64;
  const int wr = wid * 32;
  const int lrow = lane & 15, lk8 = (lane >> 4) * 8;

  // staging: 12 chunks x 1KB. chunk c=wid*3+i. lane l covers row c*16+(l>>2), col (l&3)*8.
  const int l4 = lane >> 2, lc = (lane & 3) * 8;
  const short* gsrc[3];
  short* ldst[3];
#pragma unroll
  for (int i = 0; i < 3; i++) {
    int c = wid * 3 + i;
    ldst[i] = &Sab[c * 512];
    if (c < 8) gsrc[i] = &A[(size_t)(m0 + c * 16 + l4) * K + lc];
    else       gsrc[i] = &B[(size_t)(n0 + (c - 8) * 16 + l4) * K + lc];
  }

  f32x4 acc[2][4] = {};

  for (int k0 = 0; k0 < K; k0 += 32) {
#pragma unroll
    for (int i = 0; i < 3; i++) gl_lds16(gsrc[i] + k0, ldst[i]);
    __syncthreads();
    short8 af[2], bfr[4];
#pragma unroll
    for (int m = 0; m < 2; m++) af[m] = *(const short8*)(&Sab[(wr + m * 16 + lrow) * 32 + lk8]);
#pragma unroll
    for (int n = 0; n < 4; n++) bfr[n] = *(const short8*)(&Sab[(128 + n * 16 + lrow) * 32 + lk8]);
#pragma unroll
    for (int m = 0; m < 2; m++)
#pragma unroll
      for (int n = 0; n < 4; n++)
        acc[m][n] = __builtin_amdgcn_mfma_f32_16x16x32_bf16(af[m], bfr[n], acc[m][n], 0, 0, 0);
    __syncthreads();
  }

  const int g4 = (lane >> 4) * 4;
#pragma unroll
  for (int n = 0; n < 4; n++) {
    const int col = n0 + n * 16 + lrow;
#pragma unroll
    for (int m = 0; m < 2; m++) {
#pragma unroll
      for (int i = 0; i < 4; i++) {
        const int row = m0 + wr + m * 16 + g4 + i;
        float val = acc[m][n][i];
        if (MODE == 0) {
          val = (val + bias[col]) * scl;
          int b = row >> 11, s2 = row & 2047, h = col >> 6, d = col & 63;
          ((short*)Cout)[((size_t)(b * H_CNT + h) * S_LEN + s2) * DK + d] = f2bf(val);
        } else if (MODE == 1) {
          val = val + bias[row];
          int h = row >> 6, d = row & 63, b = col >> 11, s2 = col & 2047;
          ((short*)Cout)[((size_t)(b * H_CNT + h) * DK + d) * S_LEN + s2] = f2bf(val);
        } else {
          val = val + bias[col];
          ((float*)Cout)[(size_t)row * N + col] = val;
        }
      }
    }
  }
}

// ---------------- causal flash attention (EXACT round-2 known-good) ----------
// Swapped QK^T (32x32x16 MFMA), in-register softmax, no LDS, no barriers.
// grid: (16, B*H), block 256 = 4 waves. Wave w handles q-tile {j,31-j,32+j,63-j}[w].
__global__ __launch_bounds__(256, 4) void attn2_kernel(const short* __restrict__ Q,
                                                       const short* __restrict__ Kc,
                                                       const short* __restrict__ Vt,
                                                       short* __restrict__ Oout) {
  const int bh = blockIdx.y;
  const int j = blockIdx.x;
  const int wid = threadIdx.x >> 6, lane = threadIdx.x & 63;
  const int qt = (wid == 0) ? j : (wid == 1) ? (31 - j) : (wid == 2) ? (32 + j) : (63 - j);
  const int q0 = qt * 32;
  const int ql = lane & 31, hl = lane >> 5;

  const short* Qb = Q + (size_t)bh * S_LEN * DK;
  const short* Kb = Kc + (size_t)bh * S_LEN * DK;
  const short* Vb = Vt + (size_t)bh * DK * S_LEN;

  short8 qf[4];
#pragma unroll
  for (int kk = 0; kk < 4; kk++)
    qf[kk] = *(const short8*)(&Qb[(q0 + ql) * DK + kk * 16 + hl * 8]);

  f32x16 oacc[2] = {};
  float mr = -1e30f, lr = 0.f;

  const int ntiles = qt + 1;
  for (int t = 0; t < ntiles; t++) {
    const int kv0 = t * 32;
    // S^T[kv, q] = sum_k K[kv,k] * Q[q,k]
    f32x16 st = {};
#pragma unroll
    for (int kk = 0; kk < 4; kk++) {
      short8 kf = *(const short8*)(&Kb[(kv0 + ql) * DK + kk * 16 + hl * 8]);
      st = __builtin_amdgcn_mfma_f32_32x32x16_bf16(kf, qf[kk], st, 0, 0, 0);
    }
    // V loads for this tile (consumed after softmax)
    short8 vf[2][2];
#pragma unroll
    for (int td = 0; td < 2; td++)
#pragma unroll
      for (int kk = 0; kk < 2; kk++)
        vf[td][kk] = *(const short8*)(&Vb[(size_t)(td * 32 + ql) * S_LEN + kv0 + kk * 16 + hl * 8]);

    float p[16];
#pragma unroll
    for (int r = 0; r < 16; r++) p[r] = st[r];
    if (t == ntiles - 1) {
#pragma unroll
      for (int r = 0; r < 16; r++) {
        int kvr = (r & 3) + 8 * (r >> 2) + 4 * hl;
        if (kvr > ql) p[r] = -1e30f;
      }
    }
    float pm = p[0];
#pragma unroll
    for (int r = 1; r < 16; r++) pm = fmaxf(pm, p[r]);
    pm = fmaxf(pm, __shfl_xor(pm, 32, 64));
    if (!__all(pm <= mr + 8.f)) {
      float mnew = fmaxf(mr, pm);
      float al = __builtin_amdgcn_exp2f(mr - mnew);
      lr *= al;
#pragma unroll
      for (int td = 0; td < 2; td++)
#pragma unroll
        for (int r = 0; r < 16; r++) oacc[td][r] *= al;
      mr = mnew;
    }
    float rs = 0.f;
#pragma unroll
    for (int r = 0; r < 16; r++) {
      p[r] = __builtin_amdgcn_exp2f(p[r] - mr);
      rs += p[r];
    }
    rs += __shfl_xor(rs, 32, 64);
    lr += rs;

    unsigned wpk[8];
#pragma unroll
    for (int tt = 0; tt < 8; tt++) wpk[tt] = cvt_pk_bf16(p[2 * tt], p[2 * tt + 1]);
    union { short8 s; unsigned u[4]; } bf0, bf1;
    {
      unsigned xa = __shfl_xor((int)wpk[2], 32, 64), xb = __shfl_xor((int)wpk[0], 32, 64);
      bf0.u[0] = hl ? xa : wpk[0];
      bf0.u[2] = hl ? wpk[2] : xb;
    }
    {
      unsigned xa = __shfl_xor((int)wpk[3], 32, 64), xb = __shfl_xor((int)wpk[1], 32, 64);
      bf0.u[1] = hl ? xa : wpk[1];
      bf0.u[3] = hl ? wpk[3] : xb;
    }
    {
      unsigned xa = __shfl_xor((int)wpk[6], 32, 64), xb = __shfl_xor((int)wpk[4], 32, 64);
      bf1.u[0] = hl ? xa : wpk[4];
      bf1.u[2] = hl ? wpk[6] : xb;
    }
    {
      unsigned xa = __shfl_xor((int)wpk[7], 32, 64), xb = __shfl_xor((int)wpk[5], 32, 64);
      bf1.u[1] = hl ? xa : wpk[5];
      bf1.u[3] = hl ? wpk[7] : xb;
    }

#pragma unroll
    for (int td = 0; td < 2; td++) {
      oacc[td] = __builtin_amdgcn_mfma_f32_32x32x16_bf16(vf[td][0], bf0.s, oacc[td], 0, 0, 0);
      oacc[td] = __builtin_amdgcn_mfma_f32_32x32x16_bf16(vf[td][1], bf1.s, oacc[td], 0, 0, 0);
    }
  }

  const float inv = __builtin_amdgcn_rcpf(lr);
  const int b = bh >> 4, h = bh & 15;
  unsigned* ob = (unsigned*)Oout + ((size_t)b * S_LEN + q0 + ql) * (DMODEL / 2) + h * (DK / 2);
#pragma unroll
  for (int td = 0; td < 2; td++)
#pragma unroll
    for (int tt = 0; tt < 8; tt++) {
      unsigned pkv = cvt_pk_bf16(oacc[td][2 * tt] * inv, oacc[td][2 * tt + 1] * inv);
      ob[td * 16 + (tt & 1) + 4 * (tt >> 1) + 2 * hl] = pkv;
    }
}

// ---------------- launcher ----------------
extern "C" void kernel_launch(void* const* d_in, const int* in_sizes, int n_in,
                              void* d_out, int out_size, void* d_ws, size_t ws_size,
                              hipStream_t stream) {
  (void)in_sizes; (void)n_in; (void)out_size; (void)ws_size;
  const float* query = (const float*)d_in[0];
  const float* key_i = (const float*)d_in[1];
  const float* value = (const float*)d_in[2];
  const float* w_q = (const float*)d_in[4];
  const float* b_q = (const float*)d_in[5];
  const float* w_k = (const float*)d_in[6];
  const float* b_k = (const float*)d_in[7];
  const float* w_v = (const float*)d_in[8];
  const float* b_v = (const float*)d_in[9];
  const float* w_o = (const float*)d_in[10];
  const float* b_o = (const float*)d_in[11];

  const size_t XE = (size_t)BATCH * S_LEN * DMODEL;  // 8388608
  const size_t WE = (size_t)DMODEL * DMODEL;         // 1048576

  short* xq = (short*)d_ws;
  short* xk = xq + XE;
  short* xv = xk + XE;
  short* wq = xv + XE;
  short* wk = wq + WE;
  short* wv = wk + WE;
  short* wo = wv + WE;
  short* qb = wo + WE;
  short* kb = qb + XE;
  short* vtb = kb + XE;
  short* attnb = xq;  // reuse: xq dead after Q projection

  const int M = BATCH * S_LEN;  // 8192

  int n8x = (int)(XE / 8), n8w = (int)(WE / 8);
  cast_kernel<<<dim3((n8x + 255) / 256), 256, 0, stream>>>(query, xq, n8x);
  cast_kernel<<<dim3((n8x + 255) / 256), 256, 0, stream>>>(key_i, xk, n8x);
  cast_kernel<<<dim3((n8x + 255) / 256), 256, 0, stream>>>(value, xv, n8x);
  cast_kernel<<<dim3((n8w + 255) / 256), 256, 0, stream>>>(w_q, wq, n8w);
  cast_kernel<<<dim3((n8w + 255) / 256), 256, 0, stream>>>(w_k, wk, n8w);
  cast_kernel<<<dim3((n8w + 255) / 256), 256, 0, stream>>>(w_v, wv, n8w);
  cast_kernel<<<dim3((n8w + 255) / 256), 256, 0, stream>>>(w_o, wo, n8w);

  // Q pre-scaled by 1/sqrt(dk) * log2(e): attention works in exp2 domain
  const float qscale = 0.125f * 1.44269504088896f;

  gemm_bt<0><<<1024, 256, 0, stream>>>(xq, wq, b_q, qb, M, DMODEL, DMODEL, qscale);
  gemm_bt<0><<<1024, 256, 0, stream>>>(xk, wk, b_k, kb, M, DMODEL, DMODEL, 1.f);
  gemm_bt<1><<<1024, 256, 0, stream>>>(wv, xv, b_v, vtb, DMODEL, M, DMODEL, 1.f);

  attn2_kernel<<<dim3(16, BATCH * H_CNT), 256, 0, stream>>>(qb, kb, vtb, attnb);

  gemm_bt<2><<<1024, 256, 0, stream>>>(attnb, wo, b_o, d_out, M, DMODEL, DMODEL, 1.f);
}